// Round 9
// baseline (420.422 us; speedup 1.0000x reference)
//
#include <hip/hip_runtime.h>
#include <math.h>

// TemporalSNNClassifier — bit-exact fp32 emulation (absmax 0.0 since r2).
//
// r7 evidence: VGPR pinned at 128 even with launch_bounds(256,1) -> the
// allocator meets a 128-reg budget by sinking the 32 loop-invariant W2
// b128 loads into the t-loop; 8 waves/CU x 32 reloads/t through one L1 ->
// L1-service-bound, VALUBusy 40-45%, dur 325-440us across r4-r7.
// r8 failed to compile: "+v" ties on float4 are "tied indirect" operands.
// r9: W2 as 128 SCALAR floats, tied by 8 empty asm statements (16 scalar
// "+v" each) at the top of every t-iteration -> values are asm outputs,
// compiler cannot remat/reload them from memory; loads stay hoisted and
// W2 stays register-resident (~200 VGPRs, still 2 waves/SIMD — free).
//
// FROZEN numerics: k-ascending single-accumulator fmaf chains (GEMM1),
// h-ascending 0..127 masked-add chain (==fmaf(s,w,a), s in {0,1}, acc never
// -0), bias as one separate add, leaky update ((0.9f*mem)+cur)-reset with
// contraction off, spike <=> mem > 1.0f, reset_t == spk_{t-1}.

#define T_STEPS 64
#define IN_DIM  256
#define HID     128
#define NCLS    8
#define RPB     32    // rows per block (4 waves x 8 rows)
#define NTHR    256

// masked add term: bit b of m set -> w, else +0.0f (v_bfe_i32 + v_and).
__device__ __forceinline__ float mand(unsigned int m, int b, float w) {
#if __has_builtin(__builtin_amdgcn_sbfe)
    int sel = __builtin_amdgcn_sbfe((int)m, b, 1);   // 0 or -1
#else
    int sel = ((int)(m << (31 - b))) >> 31;          // folds to v_bfe_i32
#endif
    return __int_as_float(sel & __float_as_int(w));
}

__global__ __launch_bounds__(NTHR, 1)
void snn_fp32(const float* __restrict__ x, const float* __restrict__ W1,
              const float* __restrict__ b1, const float* __restrict__ W2,
              const float* __restrict__ b2, float* __restrict__ out)
{
#pragma clang fp contract(off)
    const int tid  = threadIdx.x;
    const int lane = tid & 63;
    const int r    = tid >> 3;           // block row 0..31 (wave w owns 8w..8w+7)
    const int q    = tid & 7;            // phase-a h-block / phase-b class
    const int row  = blockIdx.x * RPB + r;

    // ---- GEMM1: cur1[h] = fmaf-chain_k( x[row,k]*W1[h,k] ) + b1[h] ----
    float cur1[16];
    #pragma unroll
    for (int i = 0; i < 16; ++i) cur1[i] = 0.0f;

    const float* xrow = x + (size_t)row * IN_DIM;
    const float* w1b  = W1 + (size_t)(q * 16) * IN_DIM;
    #pragma unroll 1
    for (int k = 0; k < IN_DIM; k += 4) {
        const float4 xv = *(const float4*)(xrow + k);
        #pragma unroll
        for (int i = 0; i < 16; ++i) {
            const float4 wv = *(const float4*)(w1b + i * IN_DIM + k);
            float c = cur1[i];
            c = fmaf(xv.x, wv.x, c);     // k ascending, single accumulator
            c = fmaf(xv.y, wv.y, c);
            c = fmaf(xv.z, wv.z, c);
            c = fmaf(xv.w, wv.w, c);
            cur1[i] = c;
        }
    }
    #pragma unroll
    for (int i = 0; i < 16; ++i)
        cur1[i] = cur1[i] + b1[q * 16 + i];

    // ---- W2[class=q][*] as 128 scalar floats (pinned to VGPRs below) ----
    const float* wsrc = W2 + (size_t)q * HID;
#define LD4(n) const float4 v##n = *(const float4*)(wsrc + 4 * (n)); \
               float s##n##_0 = v##n.x, s##n##_1 = v##n.y,           \
                     s##n##_2 = v##n.z, s##n##_3 = v##n.w;
    LD4(0)  LD4(1)  LD4(2)  LD4(3)  LD4(4)  LD4(5)  LD4(6)  LD4(7)
    LD4(8)  LD4(9)  LD4(10) LD4(11) LD4(12) LD4(13) LD4(14) LD4(15)
    LD4(16) LD4(17) LD4(18) LD4(19) LD4(20) LD4(21) LD4(22) LD4(23)
    LD4(24) LD4(25) LD4(26) LD4(27) LD4(28) LD4(29) LD4(30) LD4(31)
#undef LD4
    const float b2c = b2[q];

    // bpermute byte-addresses for words 0..3 of this lane's row
    const int pbase = (lane << 2) & 0xE0;    // (lane&0x38)*4

    float mem1[16];
    #pragma unroll
    for (int i = 0; i < 16; ++i) mem1[i] = 0.0f;
    unsigned int pmk = 0;                // previous spike mask (reset source)
    float m2 = 0.0f, r2 = 0.0f, o = 0.0f;

#define TIE4(n) "+v"(s##n##_0), "+v"(s##n##_1), "+v"(s##n##_2), "+v"(s##n##_3)

    #pragma unroll 1
    for (int t = 0; t < T_STEPS; ++t) {
        // Pin W2 in VGPRs: empty asm, scalar read/write ties (zero instrs).
        // Values become asm outputs -> cannot be rematerialized from memory.
        asm volatile("" : TIE4(0),  TIE4(1),  TIE4(2),  TIE4(3));
        asm volatile("" : TIE4(4),  TIE4(5),  TIE4(6),  TIE4(7));
        asm volatile("" : TIE4(8),  TIE4(9),  TIE4(10), TIE4(11));
        asm volatile("" : TIE4(12), TIE4(13), TIE4(14), TIE4(15));
        asm volatile("" : TIE4(16), TIE4(17), TIE4(18), TIE4(19));
        asm volatile("" : TIE4(20), TIE4(21), TIE4(22), TIE4(23));
        asm volatile("" : TIE4(24), TIE4(25), TIE4(26), TIE4(27));
        asm volatile("" : TIE4(28), TIE4(29), TIE4(30), TIE4(31));

        // phase a: leaky layer-1 for 16 h units (numpy op order, no contract)
        unsigned int mk = 0;
        #pragma unroll
        for (int i = 0; i < 16; ++i) {
            float tmp = 0.9f * mem1[i];            // rounded mul
            tmp = tmp + cur1[i];                   // rounded add
            float m = tmp - mand(pmk, i, 1.0f);    // rounded sub (reset=prev spk)
            mem1[i] = m;
            mk |= (m > 1.0f) ? (1u << i) : 0u;
        }
        pmk = mk;

        // pack pairs: even-q lanes hold word for (q, q+1)
        const int nb = __shfl_xor((int)mk, 1, 64);
        const int lo = (q & 1) ? nb : (int)mk;
        const int hi = (q & 1) ? (int)mk : nb;
        const int word = lo | (hi << 16);

        // pull this row's 4 words from lanes (row*8 + 2j)
        const unsigned int m0 = (unsigned int)__builtin_amdgcn_ds_bpermute(pbase + 0,  word);
        const unsigned int m1 = (unsigned int)__builtin_amdgcn_ds_bpermute(pbase + 8,  word);
        const unsigned int m2w = (unsigned int)__builtin_amdgcn_ds_bpermute(pbase + 16, word);
        const unsigned int m3 = (unsigned int)__builtin_amdgcn_ds_bpermute(pbase + 24, word);

        // phase b: h-ascending 128-step masked-add chain, all-register
        float a = 0.0f;
#define STEP4(mw, n, b0) \
        a = a + mand(mw, (b0) + 0, s##n##_0); \
        a = a + mand(mw, (b0) + 1, s##n##_1); \
        a = a + mand(mw, (b0) + 2, s##n##_2); \
        a = a + mand(mw, (b0) + 3, s##n##_3);
        STEP4(m0, 0,  0)  STEP4(m0, 1,  4)  STEP4(m0, 2,  8)  STEP4(m0, 3,  12)
        STEP4(m0, 4,  16) STEP4(m0, 5,  20) STEP4(m0, 6,  24) STEP4(m0, 7,  28)
        STEP4(m1, 8,  0)  STEP4(m1, 9,  4)  STEP4(m1, 10, 8)  STEP4(m1, 11, 12)
        STEP4(m1, 12, 16) STEP4(m1, 13, 20) STEP4(m1, 14, 24) STEP4(m1, 15, 28)
        STEP4(m2w, 16, 0)  STEP4(m2w, 17, 4)  STEP4(m2w, 18, 8)  STEP4(m2w, 19, 12)
        STEP4(m2w, 20, 16) STEP4(m2w, 21, 20) STEP4(m2w, 22, 24) STEP4(m2w, 23, 28)
        STEP4(m3, 24, 0)  STEP4(m3, 25, 4)  STEP4(m3, 26, 8)  STEP4(m3, 27, 12)
        STEP4(m3, 28, 16) STEP4(m3, 29, 20) STEP4(m3, 30, 24) STEP4(m3, 31, 28)
#undef STEP4

        // layer-2 leaky update (numpy op order)
        const float c2 = a + b2c;
        float t2 = 0.9f * m2; t2 = t2 + c2; m2 = t2 - r2;
        r2 = (m2 > 1.0f) ? 1.0f : 0.0f;
        o  = o + r2;
    }
#undef TIE4

    // (row = r, class = q) -> coalesced store (out + blk*256 + tid)
    out[(size_t)row * NCLS + q] = o;
}

extern "C" void kernel_launch(void* const* d_in, const int* in_sizes, int n_in,
                              void* d_out, int out_size, void* d_ws, size_t ws_size,
                              hipStream_t stream) {
    const float* x  = (const float*)d_in[0];
    const float* W1 = (const float*)d_in[1];
    const float* b1 = (const float*)d_in[2];
    const float* W2 = (const float*)d_in[3];
    const float* b2 = (const float*)d_in[4];
    float* out = (float*)d_out;

    const int batch = in_sizes[0] / IN_DIM;   // 16384
    const int grid  = batch / RPB;            // 512 blocks
    snn_fp32<<<grid, NTHR, 0, stream>>>(x, W1, b1, W2, b2, out);
}

// Round 10
// 418.908 us; speedup vs baseline: 1.0036x; 1.0036x over previous
//
#include <hip/hip_runtime.h>
#include <math.h>

// TemporalSNNClassifier — bit-exact fp32 emulation (absmax 0.0 since r2).
//
// r4-r9: every W2 storage vehicle (LDS, VGPR-ask, launch_bounds, asm-pin)
// lands 325-440us; VGPR_Count shows the allocator always wins. r10 does two
// things: (1) SPLIT into two dispatches so rocprof finally shows how time
// divides between GEMM and t-loop; (2) W2 through SGPRs: class is wave-
// uniform (readfirstlane) -> W2 row address uniform -> s_load into scalar
// regs; chain step v_bfe + v_and(s,v) + v_add needs no W2 VGPRs at all.
//
// FROZEN numerics: k-ascending single-accumulator fmaf chains (GEMM1),
// h-ascending 0..127 masked-add chain (==fmaf(s,w,a), s in {0,1}, acc never
// -0), bias as one separate add, leaky update ((0.9f*mem)+cur)-reset with
// contraction off, spike <=> mem > 1.0f, reset_t == spk_{t-1}.

#define T_STEPS 64
#define IN_DIM  256
#define HID     128
#define NCLS    8

// ---------------- kernel A: cur1 GEMM -> ws ----------------
#define A_RPB  32
#define A_THR  256

__global__ __launch_bounds__(A_THR, 2)
void snn_gemm(const float* __restrict__ x, const float* __restrict__ W1,
              const float* __restrict__ b1, float* __restrict__ ws)
{
#pragma clang fp contract(off)
    const int tid = threadIdx.x;
    const int r   = tid >> 3;
    const int q   = tid & 7;
    const int row = blockIdx.x * A_RPB + r;

    float cur1[16];
    #pragma unroll
    for (int i = 0; i < 16; ++i) cur1[i] = 0.0f;

    const float* xrow = x + (size_t)row * IN_DIM;
    const float* w1b  = W1 + (size_t)(q * 16) * IN_DIM;
    #pragma unroll 1
    for (int k = 0; k < IN_DIM; k += 4) {
        const float4 xv = *(const float4*)(xrow + k);
        #pragma unroll
        for (int i = 0; i < 16; ++i) {
            const float4 wv = *(const float4*)(w1b + i * IN_DIM + k);
            float c = cur1[i];
            c = fmaf(xv.x, wv.x, c);     // k ascending, single accumulator
            c = fmaf(xv.y, wv.y, c);
            c = fmaf(xv.z, wv.z, c);
            c = fmaf(xv.w, wv.w, c);
            cur1[i] = c;
        }
    }
    float* dst = ws + (size_t)row * HID + q * 16;
    #pragma unroll
    for (int i = 0; i < 4; ++i) {
        float4 v;
        v.x = cur1[4*i+0] + b1[q*16 + 4*i+0];   // one rounded add each
        v.y = cur1[4*i+1] + b1[q*16 + 4*i+1];
        v.z = cur1[4*i+2] + b1[q*16 + 4*i+2];
        v.w = cur1[4*i+3] + b1[q*16 + 4*i+3];
        *(float4*)(dst + 4*i) = v;
    }
}

// ---------------- kernel B: temporal loop ----------------
#define B_RPB  64
#define B_THR  512   // 8 waves = 8 classes

__global__ __launch_bounds__(B_THR, 1)
void snn_tloop(const float* __restrict__ ws, const float* __restrict__ W2,
               const float* __restrict__ b2, float* __restrict__ out)
{
#pragma clang fp contract(off)
    __shared__ unsigned short smask[2][B_RPB * 8];   // [buf][row*8+q]

    const int tid = threadIdx.x;
    const int r   = tid >> 3;            // phase-a row 0..63
    const int q   = tid & 7;             // phase-a h-block
    const int row = blockIdx.x * B_RPB + r;

    // phase-b identity: class = wave (FORCED uniform), row = lane
    const int wcls = __builtin_amdgcn_readfirstlane(tid >> 6);
    const int ln   = tid & 63;

    // cur1 for this thread's 16 h units (one-time coalesced-ish load)
    float cur1[16];
    {
        const float* src = ws + (size_t)row * HID + q * 16;
        #pragma unroll
        for (int i = 0; i < 4; ++i) {
            const float4 v = *(const float4*)(src + 4 * i);
            cur1[4*i+0] = v.x; cur1[4*i+1] = v.y;
            cur1[4*i+2] = v.z; cur1[4*i+3] = v.w;
        }
    }

    // W2 row for this wave: UNIFORM address -> scalar loads (SGPRs).
    const float* __restrict__ w2u = W2 + (size_t)wcls * HID;
    const float b2c = b2[wcls];

    float mem1[16], spk1[16];
    #pragma unroll
    for (int i = 0; i < 16; ++i) { mem1[i] = 0.0f; spk1[i] = 0.0f; }
    float m2 = 0.0f, r2 = 0.0f, o = 0.0f;

    #pragma unroll 1
    for (int t = 0; t < T_STEPS; ++t) {
        // phase a: leaky layer-1 update (numpy op order, no contraction)
        unsigned int mk = 0;
        #pragma unroll
        for (int i = 0; i < 16; ++i) {
            float tmp = 0.9f * mem1[i];   // rounded mul
            tmp = tmp + cur1[i];          // rounded add
            float m = tmp - spk1[i];      // rounded sub
            mem1[i] = m;
            const bool fire = (m > 1.0f);
            spk1[i] = fire ? 1.0f : 0.0f;
            mk |= fire ? (1u << i) : 0u;
        }
        smask[t & 1][r * 8 + q] = (unsigned short)mk;
        __syncthreads();   // double buffer -> one barrier per timestep

        // phase b: row ln's 128 bits, h-ascending masked-add chain.
        // W2 terms come from SGPRs (s_load): v_bfe + v_and(s,v) + v_add.
        const uint4 mv = *(const uint4*)&smask[t & 1][ln * 8];
        const unsigned int mw[4] = {mv.x, mv.y, mv.z, mv.w};
        float a = 0.0f;
        #pragma unroll
        for (int j = 0; j < 4; ++j) {
            const unsigned int m = mw[j];
            #pragma unroll
            for (int b = 0; b < 32; ++b) {
                const int sel = ((int)(m << (31 - b))) >> 31;   // v_bfe_i32
                a = a + __int_as_float(sel & __float_as_int(w2u[j * 32 + b]));
            }
        }
        const float c2 = a + b2c;
        float t2 = 0.9f * m2; t2 = t2 + c2; m2 = t2 - r2;
        r2 = (m2 > 1.0f) ? 1.0f : 0.0f;
        o  = o + r2;
    }

    out[(size_t)(blockIdx.x * B_RPB + ln) * NCLS + wcls] = o;
}

extern "C" void kernel_launch(void* const* d_in, const int* in_sizes, int n_in,
                              void* d_out, int out_size, void* d_ws, size_t ws_size,
                              hipStream_t stream) {
    const float* x  = (const float*)d_in[0];
    const float* W1 = (const float*)d_in[1];
    const float* b1 = (const float*)d_in[2];
    const float* W2 = (const float*)d_in[3];
    const float* b2 = (const float*)d_in[4];
    float* out = (float*)d_out;
    float* cur_ws = (float*)d_ws;        // [BATCH x HID] = 8 MB

    const int batch = in_sizes[0] / IN_DIM;        // 16384
    snn_gemm<<<batch / A_RPB, A_THR, 0, stream>>>(x, W1, b1, cur_ws);
    snn_tloop<<<batch / B_RPB, B_THR, 0, stream>>>(cur_ws, W2, b2, out);
}

// Round 11
// 244.768 us; speedup vs baseline: 1.7176x; 1.7114x over previous
//
#include <hip/hip_runtime.h>
#include <math.h>

// TemporalSNNClassifier — bit-exact fp32 emulation (absmax 0.0 since r2).
//
// r10 split-profile evidence:
//  A (gemm) 235us @ VALU 8%: scattered global b128 wave-loads cost ~65cyc
//    each (1KB return @ ~16B/cyc) -> W1 re-reads from global are the cost.
//    r11-A: W1 staged in LDS [kq][h] float4 (2x 64KB chunks); wave owns 8
//    rows, lane owns h=lane/lane+64 -> x addresses wave-uniform (scalar or
//    broadcast loads); main-loop LDS read = contiguous-1KB pattern (~12cyc).
//  B (tloop) ~184us: SGPR=112 maxed (cap 102/wave) -> W2 re-s_load'ed every
//    timestep, lgkm waits serialized with the chain. r11-B: W2 in LDS, read
//    at wave-uniform addresses (class=wave) -> broadcast ds_read_b128
//    co-issued under the 3-VALU/step chain.
//
// FROZEN numerics: k-ascending single-accumulator fmaf chains (GEMM1),
// h-ascending 0..127 masked-add chain (==fmaf(s,w,a), s in {0,1}, acc never
// -0), bias as one separate add, leaky update ((0.9f*mem)+cur)-reset with
// contraction off, spike <=> mem > 1.0f, reset_t == spk_{t-1}.

#define T_STEPS 64
#define IN_DIM  256
#define HID     128
#define NCLS    8

// ---------------- kernel A: cur1 GEMM -> ws ----------------
// grid 256 x 512 thr (8 waves, 1 block/CU, 64 KB LDS). Wave w: rows
// blk*64 + w*8 .. +7. Lane l: h = l and l+64 (8 rows x 2 h = 16 acc).
#define A_THR  512
#define A_ROWS 64
#define KCH    32     // k-quads per chunk (128 k); 2 chunks cover K=256

__global__ __launch_bounds__(A_THR, 1)
void snn_gemm(const float* __restrict__ x, const float* __restrict__ W1,
              const float* __restrict__ b1, float* __restrict__ ws)
{
#pragma clang fp contract(off)
    __shared__ float4 w1s[KCH * HID];    // [kq][h], 64 KB

    const int tid  = threadIdx.x;
    const int lane = tid & 63;
    const int wv   = __builtin_amdgcn_readfirstlane(tid >> 6);
    const size_t row0 = (size_t)blockIdx.x * A_ROWS + wv * 8;
    const float* __restrict__ xw = x + row0 * IN_DIM;   // wave-uniform base

    float accL[8], accH[8];
    #pragma unroll
    for (int j = 0; j < 8; ++j) { accL[j] = 0.0f; accH[j] = 0.0f; }

    // staging map: thread t -> h = t>>2, kq = (t&3)*8 + jj
    const int sh  = tid >> 2;
    const int skq = (tid & 3) * 8;

    #pragma unroll 1
    for (int ch = 0; ch < 2; ++ch) {
        const int kbase = ch * (KCH * 4);
        #pragma unroll
        for (int jj = 0; jj < 8; ++jj) {
            const int kq = skq + jj;
            w1s[kq * HID + sh] =
                *(const float4*)(W1 + (size_t)sh * IN_DIM + kbase + kq * 4);
        }
        __syncthreads();

        #pragma unroll 2
        for (int kq = 0; kq < KCH; ++kq) {
            const float4 wL = w1s[kq * HID + lane];        // contiguous 1KB
            const float4 wH = w1s[kq * HID + 64 + lane];   // wave patterns
            const int k = kbase + kq * 4;
            #pragma unroll
            for (int j = 0; j < 8; ++j) {
                // wave-uniform address -> scalar (or broadcast) load
                const float4 xv = *(const float4*)(xw + j * IN_DIM + k);
                float aL = accL[j], aH = accH[j];
                aL = fmaf(xv.x, wL.x, aL);   // k ascending, single acc
                aL = fmaf(xv.y, wL.y, aL);
                aL = fmaf(xv.z, wL.z, aL);
                aL = fmaf(xv.w, wL.w, aL);
                aH = fmaf(xv.x, wH.x, aH);
                aH = fmaf(xv.y, wH.y, aH);
                aH = fmaf(xv.z, wH.z, aH);
                aH = fmaf(xv.w, wH.w, aH);
                accL[j] = aL; accH[j] = aH;
            }
        }
        __syncthreads();
    }

    const float bL = b1[lane], bH = b1[64 + lane];
    #pragma unroll
    for (int j = 0; j < 8; ++j) {
        ws[(row0 + j) * HID + lane]      = accL[j] + bL;   // one rounded add
        ws[(row0 + j) * HID + 64 + lane] = accH[j] + bH;   // coalesced 256B
    }
}

// ---------------- kernel B: temporal loop ----------------
#define B_RPB  64
#define B_THR  512   // 8 waves = 8 classes

__device__ __forceinline__ float mand(unsigned int m, int b, float w) {
    int sel = ((int)(m << (31 - b))) >> 31;   // v_bfe_i32
    return __int_as_float(sel & __float_as_int(w));
}

__global__ __launch_bounds__(B_THR, 1)
void snn_tloop(const float* __restrict__ ws, const float* __restrict__ W2,
               const float* __restrict__ b2, float* __restrict__ out)
{
#pragma clang fp contract(off)
    __shared__ unsigned short smask[2][B_RPB * 8];   // [buf][row*8+q]
    __shared__ float4 w2s[NCLS * (HID / 4)];         // [c][g], 4 KB

    const int tid = threadIdx.x;
    const int r   = tid >> 3;            // phase-a row 0..63
    const int q   = tid & 7;             // phase-a h-block
    const int row = blockIdx.x * B_RPB + r;

    // phase-b identity: class = wave (uniform), row = lane
    const int wcls = __builtin_amdgcn_readfirstlane(tid >> 6);
    const int ln   = tid & 63;

    if (tid < NCLS * (HID / 4))
        w2s[tid] = *(const float4*)(W2 + (tid >> 5) * HID + (tid & 31) * 4);

    float cur1[16];
    {
        const float* src = ws + (size_t)row * HID + q * 16;
        #pragma unroll
        for (int i = 0; i < 4; ++i) {
            const float4 v = *(const float4*)(src + 4 * i);
            cur1[4*i+0] = v.x; cur1[4*i+1] = v.y;
            cur1[4*i+2] = v.z; cur1[4*i+3] = v.w;
        }
    }
    const float b2c = b2[wcls];
    const float4* __restrict__ w2u = &w2s[wcls * (HID / 4)];

    float mem1[16], spk1[16];
    #pragma unroll
    for (int i = 0; i < 16; ++i) { mem1[i] = 0.0f; spk1[i] = 0.0f; }
    float m2 = 0.0f, r2 = 0.0f, o = 0.0f;

    __syncthreads();   // w2s staged

    #pragma unroll 1
    for (int t = 0; t < T_STEPS; ++t) {
        // phase a: leaky layer-1 update (numpy op order, no contraction)
        unsigned int mk = 0;
        #pragma unroll
        for (int i = 0; i < 16; ++i) {
            float tmp = 0.9f * mem1[i];   // rounded mul
            tmp = tmp + cur1[i];          // rounded add
            float m = tmp - spk1[i];      // rounded sub
            mem1[i] = m;
            const bool fire = (m > 1.0f);
            spk1[i] = fire ? 1.0f : 0.0f;
            mk |= fire ? (1u << i) : 0u;
        }
        smask[t & 1][r * 8 + q] = (unsigned short)mk;
        __syncthreads();   // double buffer -> one barrier per timestep

        // phase b: h-ascending 128-step masked-add chain; W2 quads come
        // from LDS at wave-uniform addresses (broadcast b128, DS co-issue)
        const uint4 mv = *(const uint4*)&smask[t & 1][ln * 8];
        const unsigned int mw[4] = {mv.x, mv.y, mv.z, mv.w};
        float a = 0.0f;
        #pragma unroll
        for (int j = 0; j < 4; ++j) {
            const unsigned int m = mw[j];
            #pragma unroll
            for (int g = 0; g < 8; ++g) {
                const float4 wq4 = w2u[j * 8 + g];
                const int b0 = g * 4;
                a = a + mand(m, b0 + 0, wq4.x);   // strict h order
                a = a + mand(m, b0 + 1, wq4.y);
                a = a + mand(m, b0 + 2, wq4.z);
                a = a + mand(m, b0 + 3, wq4.w);
            }
        }
        const float c2 = a + b2c;
        float t2 = 0.9f * m2; t2 = t2 + c2; m2 = t2 - r2;
        r2 = (m2 > 1.0f) ? 1.0f : 0.0f;
        o  = o + r2;
    }

    out[(size_t)(blockIdx.x * B_RPB + ln) * NCLS + wcls] = o;
}

extern "C" void kernel_launch(void* const* d_in, const int* in_sizes, int n_in,
                              void* d_out, int out_size, void* d_ws, size_t ws_size,
                              hipStream_t stream) {
    const float* x  = (const float*)d_in[0];
    const float* W1 = (const float*)d_in[1];
    const float* b1 = (const float*)d_in[2];
    const float* W2 = (const float*)d_in[3];
    const float* b2 = (const float*)d_in[4];
    float* out = (float*)d_out;
    float* cur_ws = (float*)d_ws;        // [BATCH x HID] = 8 MB

    const int batch = in_sizes[0] / IN_DIM;          // 16384
    snn_gemm<<<batch / A_ROWS, A_THR, 0, stream>>>(x, W1, b1, cur_ws);
    snn_tloop<<<batch / B_RPB, B_THR, 0, stream>>>(cur_ws, W2, b2, out);
}

// Round 12
// 193.290 us; speedup vs baseline: 2.1751x; 1.2663x over previous
//
#include <hip/hip_runtime.h>
#include <math.h>

// TemporalSNNClassifier — bit-exact fp32 emulation (absmax 0.0 since r2).
//
// r11 evidence: tloop 162us @ VALU 82% -> issue-bound; busy-cycle math says
// chain step = 4 VALU (mask bfe path). gemm ~82us: per-thread global x-quad
// loads. r12: (A) x AND W1 in LDS for the GEMM; (B) spikes stored as FLOATS
// in LDS -> chain step collapses to ds_read_b128 + v_fmac_f32 (1 VALU/h),
// no masks, no shfl/bpermute. fmaf(s,w,a), s in {0,1} is the r2-proven
// bit-exact form. All LDS patterns are 8-distinct-address broadcasts or
// <=2-way aliasing (free).
//
// FROZEN numerics: k-ascending single-accumulator fmaf chains (GEMM1,
// chunk-ordered k), h-ascending fmaf chain over spike floats (layer 2),
// bias as one separate add, leaky update ((0.9f*mem)+cur)-reset with
// contraction off, spike <=> mem > 1.0f, reset_t == spk_{t-1}.

#define T_STEPS 64
#define IN_DIM  256
#define HID     128
#define NCLS    8

// ---------------- kernel A: cur1 GEMM -> ws ----------------
// 256 blocks x 512 thr (8 waves, 1 block/CU). Wave w: rows 8w..8w+7.
// Lane l: h = l and l+64. 4 chunks of 64 k; W1 chunk 32KB + x chunk 16KB.
#define A_THR  512
#define A_ROWS 64
#define A_KQ   16     // float4 k-quads per chunk (64 k)

__global__ __launch_bounds__(A_THR, 1)
void snn_gemm(const float* __restrict__ x, const float* __restrict__ W1,
              const float* __restrict__ b1, float* __restrict__ ws)
{
#pragma clang fp contract(off)
    __shared__ float4 w1c[A_KQ][HID];     // [kq][h]  32 KB
    __shared__ float4 xc[A_ROWS][A_KQ];   // [row][kq] 16 KB

    const int tid  = threadIdx.x;
    const int lane = tid & 63;
    const int wv   = __builtin_amdgcn_readfirstlane(tid >> 6);   // 0..7
    const size_t rowg0 = (size_t)blockIdx.x * A_ROWS;

    float accL[8], accH[8];
    #pragma unroll
    for (int j = 0; j < 8; ++j) { accL[j] = 0.0f; accH[j] = 0.0f; }

    #pragma unroll 1
    for (int ch = 0; ch < 4; ++ch) {
        const int kbase = ch * (A_KQ * 4);
        // stage W1 chunk: 2048 float4, 4 per thread, coalesced per h-row
        #pragma unroll
        for (int s = 0; s < 4; ++s) {
            const int idx = tid + s * A_THR;
            const int h = idx >> 4, kq = idx & 15;
            w1c[kq][h] = *(const float4*)(W1 + (size_t)h * IN_DIM + kbase + kq * 4);
        }
        // stage x chunk: 1024 float4, 2 per thread, coalesced per row
        #pragma unroll
        for (int s = 0; s < 2; ++s) {
            const int idx = tid + s * A_THR;
            const int rr = idx >> 4, kq = idx & 15;
            xc[rr][kq] = *(const float4*)(x + (rowg0 + rr) * IN_DIM + kbase + kq * 4);
        }
        __syncthreads();

        #pragma unroll 4
        for (int kq = 0; kq < A_KQ; ++kq) {
            const float4 wL = w1c[kq][lane];        // lane-contiguous 1KB
            const float4 wH = w1c[kq][64 + lane];
            #pragma unroll
            for (int j = 0; j < 8; ++j) {
                const float4 xv = xc[wv * 8 + j][kq];   // wave-uniform bcast
                float aL = accL[j], aH = accH[j];
                aL = fmaf(xv.x, wL.x, aL);   // k ascending, single acc
                aL = fmaf(xv.y, wL.y, aL);
                aL = fmaf(xv.z, wL.z, aL);
                aL = fmaf(xv.w, wL.w, aL);
                aH = fmaf(xv.x, wH.x, aH);
                aH = fmaf(xv.y, wH.y, aH);
                aH = fmaf(xv.z, wH.z, aH);
                aH = fmaf(xv.w, wH.w, aH);
                accL[j] = aL; accH[j] = aH;
            }
        }
        __syncthreads();
    }

    const float bL = b1[lane], bH = b1[64 + lane];
    #pragma unroll
    for (int j = 0; j < 8; ++j) {
        const size_t rg = rowg0 + wv * 8 + j;
        ws[rg * HID + lane]      = accL[j] + bL;   // one rounded add each
        ws[rg * HID + 64 + lane] = accH[j] + bH;   // coalesced 256B stores
    }
}

// ---------------- kernel B: temporal loop ----------------
// 512 blocks x 256 thr (4 waves), 2 blocks/CU. Phase a: thread (r=tid>>3,
// q=tid&7) owns 16 h, writes spike FLOATS to spk[buf][r][*]. Phase b:
// lane = 8*rloc + cls -> 8 lanes share a row (broadcast reads), chain =
// 32 x (ds_read_b128 spikes + ds_read_b128 W2 + 4 v_fmac).
#define B_RPB  32
#define B_THR  256
#define BSTR   132    // row stride (floats): +4 pad -> disjoint bank quads

__global__ __launch_bounds__(B_THR, 2)
void snn_tloop(const float* __restrict__ ws, const float* __restrict__ W2,
               const float* __restrict__ b2, float* __restrict__ out)
{
#pragma clang fp contract(off)
    __shared__ float spk[2][B_RPB][BSTR];   // 33.8 KB spike floats
    __shared__ float w2l[NCLS][BSTR];       // 4.2 KB

    const int tid = threadIdx.x;
    const int r   = tid >> 3;            // phase-a row 0..31
    const int q   = tid & 7;             // phase-a h-block

    // stage W2: one float4 per thread
    {
        const int c = tid >> 5, g = tid & 31;
        *(float4*)&w2l[c][4 * g] = *(const float4*)(W2 + c * HID + 4 * g);
    }

    // cur1 for this thread's 16 h units
    float cur1[16];
    {
        const float* src = ws + ((size_t)blockIdx.x * B_RPB + r) * HID + q * 16;
        #pragma unroll
        for (int i = 0; i < 4; ++i) {
            const float4 v = *(const float4*)(src + 4 * i);
            cur1[4*i+0] = v.x; cur1[4*i+1] = v.y;
            cur1[4*i+2] = v.z; cur1[4*i+3] = v.w;
        }
    }

    // phase-b identity: 8 lanes per row, cls = lane&7
    const int lane = tid & 63;
    const int rloc = (tid >> 6) * 8 + (lane >> 3);   // 0..31
    const int cls  = lane & 7;
    const float b2c = b2[cls];

    float mem1[16], spk1[16];
    #pragma unroll
    for (int i = 0; i < 16; ++i) { mem1[i] = 0.0f; spk1[i] = 0.0f; }
    float m2 = 0.0f, r2 = 0.0f, o = 0.0f;

    __syncthreads();   // w2l staged

    #pragma unroll 1
    for (int t = 0; t < T_STEPS; ++t) {
        const int buf = t & 1;
        // phase a: leaky layer-1 (numpy op order, no contraction)
        #pragma unroll
        for (int i = 0; i < 16; ++i) {
            float tmp = 0.9f * mem1[i];   // rounded mul
            tmp = tmp + cur1[i];          // rounded add
            float m = tmp - spk1[i];      // rounded sub
            mem1[i] = m;
            spk1[i] = (m > 1.0f) ? 1.0f : 0.0f;
        }
        // write 16 spike floats (4 b128, <=2-way bank aliasing = free)
        #pragma unroll
        for (int s = 0; s < 4; ++s) {
            float4 v;
            v.x = spk1[4*s+0]; v.y = spk1[4*s+1];
            v.z = spk1[4*s+2]; v.w = spk1[4*s+3];
            *(float4*)&spk[buf][r][q * 16 + 4 * s] = v;
        }
        __syncthreads();   // double buffer -> one barrier per timestep

        // phase b: h-ascending fmaf chain over spike floats (bit-exact,
        // r2-proven form). Both LDS reads are 8-address broadcasts.
        float a = 0.0f;
        #pragma unroll
        for (int g = 0; g < 32; ++g) {
            const float4 sv = *(const float4*)&spk[buf][rloc][4 * g];
            const float4 wv = *(const float4*)&w2l[cls][4 * g];
            a = fmaf(sv.x, wv.x, a);   // strict h order, single acc
            a = fmaf(sv.y, wv.y, a);
            a = fmaf(sv.z, wv.z, a);
            a = fmaf(sv.w, wv.w, a);
        }
        const float c2 = a + b2c;
        float t2 = 0.9f * m2; t2 = t2 + c2; m2 = t2 - r2;
        r2 = (m2 > 1.0f) ? 1.0f : 0.0f;
        o  = o + r2;
    }

    // out idx = blk*256 + w*64 + lane -> perfectly coalesced
    out[((size_t)blockIdx.x * B_RPB + rloc) * NCLS + cls] = o;
}

extern "C" void kernel_launch(void* const* d_in, const int* in_sizes, int n_in,
                              void* d_out, int out_size, void* d_ws, size_t ws_size,
                              hipStream_t stream) {
    const float* x  = (const float*)d_in[0];
    const float* W1 = (const float*)d_in[1];
    const float* b1 = (const float*)d_in[2];
    const float* W2 = (const float*)d_in[3];
    const float* b2 = (const float*)d_in[4];
    float* out = (float*)d_out;
    float* cur_ws = (float*)d_ws;        // [BATCH x HID] = 8 MB

    const int batch = in_sizes[0] / IN_DIM;          // 16384
    snn_gemm<<<batch / A_ROWS, A_THR, 0, stream>>>(x, W1, b1, cur_ws);
    snn_tloop<<<batch / B_RPB, B_THR, 0, stream>>>(cur_ws, W2, b2, out);
}